// Round 6
// baseline (190.686 us; speedup 1.0000x reference)
//
#include <hip/hip_runtime.h>

#define BIGV 1e4f

constexpr int PX = 8;        // output px per thread in x
constexpr int D  = 4;        // rows per load batch (MLP depth)
constexpr int PH = 4;        // phases per thread
constexpr int RH = D * PH;   // 16 output rows per thread
constexpr int TY = 4;        // waves per block

// Raw row: columns x-2 .. x+9 as 2 aligned float4 + 2 halo float2.
struct Raw { float4 m0, m1; float2 L, R; };
struct Ero { float e[10]; };  // eroded columns x-1 .. x+8

__device__ __forceinline__ float min3f(float a, float b, float c) { return fminf(fminf(a, b), c); }
__device__ __forceinline__ float max3f(float a, float b, float c) { return fmaxf(fmaxf(a, b), c); }

// compile-time indexed access, i in [0,12) = img column x-2+i (folds under unroll)
__device__ __forceinline__ float rv(const Raw& r, int i) {
    switch (i) {
        case 0:  return r.L.x;  case 1:  return r.L.y;
        case 2:  return r.m0.x; case 3:  return r.m0.y;
        case 4:  return r.m0.z; case 5:  return r.m0.w;
        case 6:  return r.m1.x; case 7:  return r.m1.y;
        case 8:  return r.m1.z; case 9:  return r.m1.w;
        case 10: return r.R.x;  default: return r.R.y;
    }
}

__device__ __forceinline__ Raw load_raw(const float* __restrict__ img, int y, int x,
                                        int H, int W) {
    Raw r;
    if (y >= 0 && y < H) {                       // wave-uniform (y uniform per wave)
        const float* q = img + (size_t)y * W;
        r.m0 = *(const float4*)(q + x);
        r.m1 = *(const float4*)(q + x + 4);
        r.L = make_float2(BIGV, BIGV);
        r.R = make_float2(BIGV, BIGV);
        if (x > 0)      r.L = *(const float2*)(q + x - 2);
        if (x + PX < W) r.R = *(const float2*)(q + x + PX);
    } else {
        r.m0 = make_float4(BIGV, BIGV, BIGV, BIGV);
        r.m1 = r.m0;
        r.L = make_float2(BIGV, BIGV);
        r.R = r.L;
    }
    return r;
}

// ---- cross structuring element fast path: min/max over {C,N,S,W,E} ----
__device__ __forceinline__ Ero erode_cross(const Raw& a, const Raw& b, const Raw& c,
                                           int y, int H, int x, int W) {
    Ero e;
    if (y >= 0 && y < H) {                       // wave-uniform
#pragma unroll
        for (int j = 0; j < 10; ++j) {           // eroded column x-1+j
            float v = min3f(rv(a, j + 1), rv(b, j + 1), rv(c, j + 1));
            e.e[j] = min3f(v, rv(b, j), rv(b, j + 2));
        }
        if (x == 0)      e.e[0] = -BIGV;         // eroded col -1 -> dilation pad
        if (x + PX >= W) e.e[9] = -BIGV;         // eroded col W  -> dilation pad
    } else {
#pragma unroll
        for (int j = 0; j < 10; ++j) e.e[j] = -BIGV;
    }
    return e;
}

__device__ __forceinline__ void dilate_cross(const Ero& t, const Ero& m, const Ero& b,
                                             float4& o0, float4& o1) {
    float o[PX];
#pragma unroll
    for (int j = 0; j < PX; ++j)                 // out column x+j
        o[j] = max3f(max3f(t.e[j + 1], m.e[j + 1], b.e[j + 1]), m.e[j], m.e[j + 2]);
    o0 = make_float4(o[0], o[1], o[2], o[3]);
    o1 = make_float4(o[4], o[5], o[6], o[7]);
}

// ---- generic runtime-mask fallback (uniform branch; not taken in this bench) ----
__device__ __forceinline__ Ero erode_gen(const Raw& a, const Raw& b, const Raw& c,
                                         const bool* m, int y, int H, int x, int W) {
    Ero e;
    if (y >= 0 && y < H) {
#pragma unroll
        for (int j = 0; j < 10; ++j) {           // eroded column x-1+j
            float acc = BIGV;
#pragma unroll
            for (int k = 0; k < 9; ++k) {
                const int di = k / 3, dj = k % 3;
                const Raw& rr = (di == 0) ? a : ((di == 1) ? b : c);
                acc = fminf(acc, m[k] ? rv(rr, j + dj) : BIGV);
            }
            e.e[j] = acc;
        }
        if (x == 0)      e.e[0] = -BIGV;
        if (x + PX >= W) e.e[9] = -BIGV;
    } else {
#pragma unroll
        for (int j = 0; j < 10; ++j) e.e[j] = -BIGV;
    }
    return e;
}

__device__ __forceinline__ void dilate_gen(const Ero& t, const Ero& md, const Ero& b,
                                           const bool* m, float4& o0, float4& o1) {
    float o[PX];
#pragma unroll
    for (int j = 0; j < PX; ++j) {               // out column x+j
        float acc = -BIGV;
#pragma unroll
        for (int k = 0; k < 9; ++k) {
            const int di = k / 3, dj = k % 3;
            const Ero& ee = (di == 0) ? t : ((di == 1) ? md : b);
            acc = fmaxf(acc, m[k] ? ee.e[j + dj] : -BIGV);
        }
        o[j] = acc;
    }
    o0 = make_float4(o[0], o[1], o[2], o[3]);
    o1 = make_float4(o[4], o[5], o[6], o[7]);
}

template <bool CROSS>
__device__ __forceinline__ void run(const float* __restrict__ img, float* __restrict__ out,
                                    const bool* m, int x, int y0, int H, int W) {
    // prologue: one deep batch of 8 rows (y0-2 .. y0+5), single wait
    Raw p0 = load_raw(img, y0 - 2, x, H, W);
    Raw p1 = load_raw(img, y0 - 1, x, H, W);
    Raw A  = load_raw(img, y0,     x, H, W);     // img row yb
    Raw B  = load_raw(img, y0 + 1, x, H, W);     // img row yb+1
    Raw rc[D];                                   // current batch: img rows yb+2 .. yb+5
#pragma unroll
    for (int j = 0; j < D; ++j) rc[j] = load_raw(img, y0 + 2 + j, x, H, W);

    Ero E0 = CROSS ? erode_cross(p0, p1, A, y0 - 1, H, x, W)
                   : erode_gen(p0, p1, A, m, y0 - 1, H, x, W);   // ero(yb-1)
    Ero E1 = CROSS ? erode_cross(p1, A, B, y0, H, x, W)
                   : erode_gen(p1, A, B, m, y0, H, x, W);        // ero(yb)

#pragma unroll
    for (int p = 0; p < PH; ++p) {
        const int yb = y0 + p * D;
        // issue NEXT phase's batch first -> 12 KB/wave in flight over this compute
        Raw rn[D];
        if (p < PH - 1) {
#pragma unroll
            for (int j = 0; j < D; ++j) rn[j] = load_raw(img, yb + D + 2 + j, x, H, W);
        }
        // compute D output rows from the current batch
#pragma unroll
        for (int i = 0; i < D; ++i) {
            const int y = yb + i;
            Ero E2 = CROSS ? erode_cross(A, B, rc[i], y + 1, H, x, W)
                           : erode_gen(A, B, rc[i], m, y + 1, H, x, W);
            float4 o0, o1;
            if (CROSS) dilate_cross(E0, E1, E2, o0, o1);
            else       dilate_gen(E0, E1, E2, m, o0, o1);
            float* po = out + (size_t)y * W + x;
            *(float4*)po       = o0;
            *((float4*)po + 1) = o1;
            A = B; B = rc[i];
            E0 = E1; E1 = E2;
        }
        if (p < PH - 1) {
#pragma unroll
            for (int j = 0; j < D; ++j) rc[j] = rn[j];   // register rename after unroll
        }
    }
}

__global__ __launch_bounds__(256, 3) void opening_kernel(
    const float* __restrict__ img, const int* __restrict__ kern,
    float* __restrict__ out, int H, int W)
{
    const int lx = threadIdx.x & 63;             // lane -> x strip of 8 px
    const int ty = threadIdx.x >> 6;             // wave -> y strip (wave-uniform)
    const int x  = blockIdx.x * (64 * PX) + lx * PX;
    const int y0 = (blockIdx.y * TY + ty) * RH;
    const size_t pbase = (size_t)blockIdx.z * H * W;

    bool m[9];
#pragma unroll
    for (int k = 0; k < 9; ++k) m[k] = (kern[k] == 1);

    const bool cross = m[1] && m[3] && m[4] && m[5] && m[7] &&
                       !m[0] && !m[2] && !m[6] && !m[8];

    if (cross) run<true >(img + pbase, out + pbase, m, x, y0, H, W);
    else       run<false>(img + pbase, out + pbase, m, x, y0, H, W);
}

extern "C" void kernel_launch(void* const* d_in, const int* in_sizes, int n_in,
                              void* d_out, int out_size, void* d_ws, size_t ws_size,
                              hipStream_t stream) {
    const float* img  = (const float*)d_in[0];
    const int*   kern = (const int*)d_in[1];
    float*       out  = (float*)d_out;

    const int H = 1024, W = 1024;
    const int planes = in_sizes[0] / (H * W);    // B*C = 24

    dim3 block(256);
    dim3 grid(W / (64 * PX), H / (TY * RH), planes);  // (2, 16, 24) = 768 blocks, 12 waves/CU
    opening_kernel<<<grid, block, 0, stream>>>(img, kern, out, H, W);
}

// Round 7
// 184.190 us; speedup vs baseline: 1.0353x; 1.0353x over previous
//
#include <hip/hip_runtime.h>
#include <stdint.h>

#define BIGV 1e4f

constexpr int W     = 1024;  // image width (4 KB rows)
constexpr int TH    = 4;     // output rows per chunk
constexpr int CPB   = 4;     // chunks per block -> 16 output rows per block
constexpr int NSLOT = 16;    // LDS ring slots (rows), 64 KB total

typedef const __attribute__((address_space(1))) uint32_t glb_u32;
typedef __attribute__((address_space(3)))       uint32_t lds_u32;

__device__ __forceinline__ float min3f(float a, float b, float c) { return fminf(fminf(a, b), c); }
__device__ __forceinline__ float max3f(float a, float b, float c) { return fmaxf(fmaxf(a, b), c); }

// Stage one full img row y into ring slot (ly & 15) via async global->LDS DMA.
// One wave: 4 issues of 64 lanes x 16 B = 4 KB. OOB rows: ds_write erosion pad.
__device__ __forceinline__ void stage_row(const float* __restrict__ plane, int y, int ly,
                                          float* smem, int lane, int H) {
    float* dst = smem + (size_t)(ly & (NSLOT - 1)) * W;
    if (y >= 0 && y < H) {                        // wave-uniform
        const float* src = plane + (size_t)y * W + lane * 4;
#pragma unroll
        for (int seg = 0; seg < 4; ++seg)
            __builtin_amdgcn_global_load_lds((glb_u32*)(src + seg * 256),
                                             (lds_u32*)(dst + seg * 256), 16, 0, 0);
    } else {
        const float4 pad = make_float4(BIGV, BIGV, BIGV, BIGV);
#pragma unroll
        for (int seg = 0; seg < 4; ++seg)
            *(float4*)(dst + seg * 256 + lane * 4) = pad;
    }
}

// One img row for this thread: cols x-4 .. x+7 as three float4 from LDS.
struct T3 { float4 a, b, c; };
__device__ __forceinline__ T3 read_row(const float* smem, int ly, int tid) {
    const float4* p = (const float4*)(smem + (size_t)(ly & (NSLOT - 1)) * W);
    T3 t;
    t.b = p[tid];
    t.a = (tid > 0)       ? p[tid - 1] : make_float4(BIGV, BIGV, BIGV, BIGV);
    t.c = (tid < W/4 - 1) ? p[tid + 1] : make_float4(BIGV, BIGV, BIGV, BIGV);
    return t;
}
// compile-time indexed col access, i in [0,12) = col x-4+i (folds under unroll)
__device__ __forceinline__ float tg(const T3& t, int i) {
    switch (i) {
        case 0:  return t.a.x; case 1:  return t.a.y; case 2:  return t.a.z; case 3:  return t.a.w;
        case 4:  return t.b.x; case 5:  return t.b.y; case 6:  return t.b.z; case 7:  return t.b.w;
        case 8:  return t.c.x; case 9:  return t.c.y; case 10: return t.c.z; default: return t.c.w;
    }
}

struct E6 { float e[6]; };   // eroded cols x-1 .. x+4

template <bool CROSS>
__device__ __forceinline__ E6 ero_row(const T3& A, const T3& B, const T3& C,
                                      const bool* m, int y, int H, int x) {
    E6 e;
    if (y >= 0 && y < H) {                        // block-uniform
#pragma unroll
        for (int j = 0; j < 6; ++j) {             // eroded col x-1+j  (triplet idx 3+j)
            if (CROSS) {
                float v = min3f(tg(A, 3 + j), tg(B, 3 + j), tg(C, 3 + j));
                e.e[j] = min3f(v, tg(B, 2 + j), tg(B, 4 + j));
            } else {
                float acc = BIGV;
#pragma unroll
                for (int k = 0; k < 9; ++k) {
                    const int di = k / 3, dj = k % 3;
                    const T3& r = (di == 0) ? A : ((di == 1) ? B : C);
                    acc = fminf(acc, m[k] ? tg(r, 2 + j + dj) : BIGV);
                }
                e.e[j] = acc;
            }
        }
        if (x == 0)     e.e[0] = -BIGV;           // eroded col -1 -> dilation pad
        if (x == W - 4) e.e[5] = -BIGV;           // eroded col W  -> dilation pad
    } else {
#pragma unroll
        for (int j = 0; j < 6; ++j) e.e[j] = -BIGV;  // eroded row OOB -> dilation pad
    }
    return e;
}

template <bool CROSS>
__device__ __forceinline__ float4 dil_row(const E6& t, const E6& md, const E6& b,
                                          const bool* m) {
    float o[4];
#pragma unroll
    for (int j = 0; j < 4; ++j) {                 // out col x+j (e-idx j+1)
        if (CROSS) {
            float v = max3f(t.e[j + 1], md.e[j + 1], b.e[j + 1]);
            o[j] = max3f(v, md.e[j], md.e[j + 2]);
        } else {
            float acc = -BIGV;
#pragma unroll
            for (int k = 0; k < 9; ++k) {
                const int di = k / 3, dj = k % 3;
                const E6& ee = (di == 0) ? t : ((di == 1) ? md : b);
                acc = fmaxf(acc, m[k] ? ee.e[j + dj] : -BIGV);
            }
            o[j] = acc;
        }
    }
    return make_float4(o[0], o[1], o[2], o[3]);
}

// Compute one chunk: output rows yy..yy+3, register-rolling erosion.
template <bool CROSS>
__device__ __forceinline__ void compute_chunk(const float* smem, float* __restrict__ outp,
                                              const bool* m, int yy, int ly0, int tid, int H) {
    const int x = tid * 4;
    T3 A = read_row(smem, ly0 - 2, tid);
    T3 B = read_row(smem, ly0 - 1, tid);
    T3 C = read_row(smem, ly0,     tid);
    E6 E0 = ero_row<CROSS>(A, B, C, m, yy - 1, H, x);
    T3 D = read_row(smem, ly0 + 1, tid);
    E6 E1 = ero_row<CROSS>(B, C, D, m, yy, H, x);
#pragma unroll
    for (int i = 0; i < TH; ++i) {
        T3 N = read_row(smem, ly0 + 2 + i, tid);
        E6 E2 = ero_row<CROSS>(C, D, N, m, yy + 1 + i, H, x);
        float4 o = dil_row<CROSS>(E0, E1, E2, m);
        *(float4*)(outp + (size_t)(yy + i) * W + x) = o;
        C = D; D = N;
        E0 = E1; E1 = E2;
    }
}

__global__ __launch_bounds__(256) void opening_kernel(
    const float* __restrict__ img, const int* __restrict__ kern,
    float* __restrict__ out, int H)
{
    __shared__ float smem[NSLOT * W];             // 64 KB ring of full-width rows

    const int tid  = threadIdx.x;
    const int wv   = tid >> 6;                    // wave id (0..3)
    const int lane = tid & 63;
    const int y0   = blockIdx.x * (TH * CPB);     // first output row of this block
    const size_t pb = (size_t)blockIdx.y * H * W;
    const float* ip = img + pb;
    float*       op = out + pb;

    bool m[9];
#pragma unroll
    for (int k = 0; k < 9; ++k) m[k] = (kern[k] == 1);
    const bool cross = m[1] && m[3] && m[4] && m[5] && m[7] &&
                       !m[0] && !m[2] && !m[6] && !m[8];

    // prologue: stage ly 0..11 (img rows y0-2 .. y0+9) — covers chunks 0 and 1
#pragma unroll
    for (int j = 0; j < 3; ++j)
        stage_row(ip, y0 - 2 + wv + 4 * j, wv + 4 * j, smem, lane, H);

    for (int k = 0; k < CPB; ++k) {
        __syncthreads();                          // drains DMA: chunk k's window is ready
        // stage 4 future rows (ly 4k+12..4k+15) — completes chunk k+2's window;
        // overlaps this chunk's compute. Slots disjoint from chunk k / k+1 windows.
        if (k < CPB - 2)
            stage_row(ip, y0 + 10 + 4 * k + wv, 4 * k + 12 + wv, smem, lane, H);
        if (cross) compute_chunk<true >(smem, op, m, y0 + TH * k, 4 * k + 2, tid, H);
        else       compute_chunk<false>(smem, op, m, y0 + TH * k, 4 * k + 2, tid, H);
    }
}

extern "C" void kernel_launch(void* const* d_in, const int* in_sizes, int n_in,
                              void* d_out, int out_size, void* d_ws, size_t ws_size,
                              hipStream_t stream) {
    const float* img  = (const float*)d_in[0];
    const int*   kern = (const int*)d_in[1];
    float*       out  = (float*)d_out;

    const int H = 1024;
    const int planes = in_sizes[0] / (H * W);     // B*C = 24

    dim3 block(256);
    dim3 grid(H / (TH * CPB), planes);            // (64, 24) = 1536 blocks, 2/CU resident
    opening_kernel<<<grid, block, 0, stream>>>(img, kern, out, H);
}

// Round 8
// 182.330 us; speedup vs baseline: 1.0458x; 1.0102x over previous
//
#include <hip/hip_runtime.h>
#include <stdint.h>

#define BIGV 1e4f

constexpr int W     = 1024;  // image width (4 KB rows)
constexpr int TH    = 4;     // output rows per chunk
constexpr int CPB   = 4;     // chunks per block -> 16 output rows per block
constexpr int NSLOT = 16;    // LDS ring slots (rows), 64 KB total

typedef const __attribute__((address_space(1))) uint32_t glb_u32;
typedef __attribute__((address_space(3)))       uint32_t lds_u32;

__device__ __forceinline__ float min3f(float a, float b, float c) { return fminf(fminf(a, b), c); }
__device__ __forceinline__ float max3f(float a, float b, float c) { return fmaxf(fmaxf(a, b), c); }

// Soft barrier: wait until <=4 vmem ops outstanding (vmcnt retires in order, so the
// oldest batches + stores are drained; the just-issued 4-DMA batch stays in flight),
// then raw s_barrier. Crucially NOT __syncthreads(): no vmcnt(0) hard drain.
__device__ __forceinline__ void soft_barrier() {
    asm volatile("s_waitcnt vmcnt(4) lgkmcnt(0)\n\ts_barrier" ::: "memory");
}

// Stage one full img row y into ring slot (ly & 15) via async global->LDS DMA.
// One wave: 4 issues of 64 lanes x 16 B = 4 KB. OOB rows: ds_write erosion pad.
__device__ __forceinline__ void stage_row(const float* __restrict__ plane, int y, int ly,
                                          float* smem, int lane, int H) {
    float* dst = smem + (size_t)(ly & (NSLOT - 1)) * W;
    if (y >= 0 && y < H) {                        // wave-uniform
        const float* src = plane + (size_t)y * W + lane * 4;
#pragma unroll
        for (int seg = 0; seg < 4; ++seg)
            __builtin_amdgcn_global_load_lds((glb_u32*)(src + seg * 256),
                                             (lds_u32*)(dst + seg * 256), 16, 0, 0);
    } else {
        const float4 pad = make_float4(BIGV, BIGV, BIGV, BIGV);
#pragma unroll
        for (int seg = 0; seg < 4; ++seg)
            *(float4*)(dst + seg * 256 + lane * 4) = pad;
    }
}

// One img row for this thread: cols x-4 .. x+7 as three float4 from LDS.
struct T3 { float4 a, b, c; };
__device__ __forceinline__ T3 read_row(const float* smem, int ly, int tid) {
    const float4* p = (const float4*)(smem + (size_t)(ly & (NSLOT - 1)) * W);
    T3 t;
    t.b = p[tid];
    t.a = (tid > 0)       ? p[tid - 1] : make_float4(BIGV, BIGV, BIGV, BIGV);
    t.c = (tid < W/4 - 1) ? p[tid + 1] : make_float4(BIGV, BIGV, BIGV, BIGV);
    return t;
}
// compile-time indexed col access, i in [0,12) = col x-4+i (folds under unroll)
__device__ __forceinline__ float tg(const T3& t, int i) {
    switch (i) {
        case 0:  return t.a.x; case 1:  return t.a.y; case 2:  return t.a.z; case 3:  return t.a.w;
        case 4:  return t.b.x; case 5:  return t.b.y; case 6:  return t.b.z; case 7:  return t.b.w;
        case 8:  return t.c.x; case 9:  return t.c.y; case 10: return t.c.z; default: return t.c.w;
    }
}

struct E6 { float e[6]; };   // eroded cols x-1 .. x+4

template <bool CROSS>
__device__ __forceinline__ E6 ero_row(const T3& A, const T3& B, const T3& C,
                                      const bool* m, int y, int H, int x) {
    E6 e;
    if (y >= 0 && y < H) {                        // block-uniform
#pragma unroll
        for (int j = 0; j < 6; ++j) {             // eroded col x-1+j  (triplet idx 3+j)
            if (CROSS) {
                float v = min3f(tg(A, 3 + j), tg(B, 3 + j), tg(C, 3 + j));
                e.e[j] = min3f(v, tg(B, 2 + j), tg(B, 4 + j));
            } else {
                float acc = BIGV;
#pragma unroll
                for (int k = 0; k < 9; ++k) {
                    const int di = k / 3, dj = k % 3;
                    const T3& r = (di == 0) ? A : ((di == 1) ? B : C);
                    acc = fminf(acc, m[k] ? tg(r, 2 + j + dj) : BIGV);
                }
                e.e[j] = acc;
            }
        }
        if (x == 0)     e.e[0] = -BIGV;           // eroded col -1 -> dilation pad
        if (x == W - 4) e.e[5] = -BIGV;           // eroded col W  -> dilation pad
    } else {
#pragma unroll
        for (int j = 0; j < 6; ++j) e.e[j] = -BIGV;  // eroded row OOB -> dilation pad
    }
    return e;
}

template <bool CROSS>
__device__ __forceinline__ float4 dil_row(const E6& t, const E6& md, const E6& b,
                                          const bool* m) {
    float o[4];
#pragma unroll
    for (int j = 0; j < 4; ++j) {                 // out col x+j (e-idx j+1)
        if (CROSS) {
            float v = max3f(t.e[j + 1], md.e[j + 1], b.e[j + 1]);
            o[j] = max3f(v, md.e[j], md.e[j + 2]);
        } else {
            float acc = -BIGV;
#pragma unroll
            for (int k = 0; k < 9; ++k) {
                const int di = k / 3, dj = k % 3;
                const E6& ee = (di == 0) ? t : ((di == 1) ? md : b);
                acc = fmaxf(acc, m[k] ? ee.e[j + dj] : -BIGV);
            }
            o[j] = acc;
        }
    }
    return make_float4(o[0], o[1], o[2], o[3]);
}

// Compute one chunk: output rows yy..yy+3, register-rolling erosion.
template <bool CROSS>
__device__ __forceinline__ void compute_chunk(const float* smem, float* __restrict__ outp,
                                              const bool* m, int yy, int ly0, int tid, int H) {
    const int x = tid * 4;
    T3 A = read_row(smem, ly0 - 2, tid);
    T3 B = read_row(smem, ly0 - 1, tid);
    T3 C = read_row(smem, ly0,     tid);
    E6 E0 = ero_row<CROSS>(A, B, C, m, yy - 1, H, x);
    T3 D = read_row(smem, ly0 + 1, tid);
    E6 E1 = ero_row<CROSS>(B, C, D, m, yy, H, x);
#pragma unroll
    for (int i = 0; i < TH; ++i) {
        T3 N = read_row(smem, ly0 + 2 + i, tid);
        E6 E2 = ero_row<CROSS>(C, D, N, m, yy + 1 + i, H, x);
        float4 o = dil_row<CROSS>(E0, E1, E2, m);
        *(float4*)(outp + (size_t)(yy + i) * W + x) = o;
        C = D; D = N;
        E0 = E1; E1 = E2;
    }
}

__global__ __launch_bounds__(256) void opening_kernel(
    const float* __restrict__ img, const int* __restrict__ kern,
    float* __restrict__ out, int H)
{
    __shared__ float smem[NSLOT * W];             // 64 KB ring of full-width rows

    const int tid  = threadIdx.x;
    const int wv   = tid >> 6;                    // wave id (0..3)
    const int lane = tid & 63;
    const int y0   = blockIdx.x * (TH * CPB);     // first output row of this block
    const size_t pb = (size_t)blockIdx.y * H * W;
    const float* ip = img + pb;
    float*       op = out + pb;

    bool m[9];
#pragma unroll
    for (int k = 0; k < 9; ++k) m[k] = (kern[k] == 1);
    const bool cross = m[1] && m[3] && m[4] && m[5] && m[7] &&
                       !m[0] && !m[2] && !m[6] && !m[8];

    // prologue: stage ly 0..11 (img rows y0-2 .. y0+9) — covers chunks 0 and 1
#pragma unroll
    for (int j = 0; j < 3; ++j)
        stage_row(ip, y0 - 2 + wv + 4 * j, wv + 4 * j, smem, lane, H);

    for (int k = 0; k < CPB; ++k) {
        // soft barrier: all slots needed by chunk k are drained (vmcnt in-order),
        // while the newest 4-DMA batch (chunk k+1's future window) stays in flight.
        soft_barrier();
        // stage 4 future rows (ly 4k+12..4k+15) — chunk k+2's window; this batch has
        // TWO compute phases before its drain deadline. Slots disjoint from k, k+1.
        if (k < CPB - 2)
            stage_row(ip, y0 + 10 + 4 * k + wv, 4 * k + 12 + wv, smem, lane, H);
        if (cross) compute_chunk<true >(smem, op, m, y0 + TH * k, 4 * k + 2, tid, H);
        else       compute_chunk<false>(smem, op, m, y0 + TH * k, 4 * k + 2, tid, H);
    }
}

extern "C" void kernel_launch(void* const* d_in, const int* in_sizes, int n_in,
                              void* d_out, int out_size, void* d_ws, size_t ws_size,
                              hipStream_t stream) {
    const float* img  = (const float*)d_in[0];
    const int*   kern = (const int*)d_in[1];
    float*       out  = (float*)d_out;

    const int H = 1024;
    const int planes = in_sizes[0] / (H * W);     // B*C = 24

    dim3 block(256);
    dim3 grid(H / (TH * CPB), planes);            // (64, 24) = 1536 blocks, 2/CU resident
    opening_kernel<<<grid, block, 0, stream>>>(img, kern, out, H);
}